// Round 17
// baseline (2221.470 us; speedup 1.0000x reference)
//
#include <hip/hip_runtime.h>
#include <hip/hip_bf16.h>

#define HID 15
#define NG  60      // 4*HID
#define DIM 64
#define T2  2048
#define NLAY 4
#define BSZ 512
#define DG  8       // supersteps per barrier group (layer skew depth)
#define RS  16      // h-ring slots = 2*DG

// bf16 RNE rounding via compiler's __float2bfloat16 — PROVEN R15/R16.
__device__ __forceinline__ float bfr(float x) {
    __hip_bfloat16 h = __float2bfloat16(x);
    unsigned short u;
    __builtin_memcpy(&u, &h, 2);
    return __uint_as_float(((unsigned)u) << 16);
}
// one bf16-rounded multiply-accumulate term: acc = bf(acc + bf(a*b))
#define CH(acc, a, b) acc = bfr(acc + bfr((a) * (b)))

__device__ __forceinline__ float tanh_np(float z) {
    const float e = __expf(-2.0f * z);
    return bfr((1.0f - e) / (1.0f + e));
}
__device__ __forceinline__ float sig_np(float z) {
    const float e   = bfr(__expf(-z));
    const float den = bfr(1.0f + e);
    return bfr(1.0f / den);
}
__device__ __forceinline__ float b2f(unsigned b) {
    return __uint_as_float(b << 16);
}

// ============ Phase 1: layer-0 projection, FOUR rows per wave ============
// proj0 is latency-bound on the 64-link serial add/cvt chain (measured 27%
// of issue roofline). 4 independent row-chains per wave raise in-flight
// chains per SIMD from 16 (8wv x 2) to ~24 (6wv x 4) despite the VGPR-driven
// occupancy drop. Per-row op order identical to R13-R16 -> identical pa bytes.
// Dead quads (t >= len) skipped before loading (R16 liveness scan).
__global__ __launch_bounds__(256, 1)
void proj0(const float* __restrict__ emb,
           const int*   __restrict__ lengths,
           const float* __restrict__ Wih0,
           unsigned short* __restrict__ pa)
{
    const int wave = threadIdx.x >> 6;
    const int lane = threadIdx.x & 63;
    const int g    = (lane < NG) ? lane : (NG - 1);

    __shared__ __align__(16) float xrow[4][4][64];   // [wave][row][elem]

    float wx[DIM];
    #pragma unroll
    for (int q = 0; q < 16; ++q) {
        float4 w = *(const float4*)(Wih0 + g*DIM + 4*q);
        wx[4*q+0] = bfr(w.x); wx[4*q+1] = bfr(w.y);
        wx[4*q+2] = bfr(w.z); wx[4*q+3] = bfr(w.w);
    }

    const int nquads = (BSZ * T2) / 4;       // quad = rows 4q..4q+3 (same seq)
    const int stride = gridDim.x * 4;

    // quad q live iff t = 4q mod T2 < len[4q / T2] (row 0 of the quad live)
    #define QLIVE(p) ((((4*(p)) & (T2-1)) < lengths[(4*(p)) >> 11]))

    int q = blockIdx.x * 4 + wave;
    while (q < nquads && !QLIVE(q)) q += stride;    // first live quad

    float xr0 = 0.f, xr1 = 0.f, xr2 = 0.f, xr3 = 0.f;
    if (q < nquads) {                        // prime pipeline
        const size_t base = (size_t)(4*q) * DIM + lane;
        xr0 = emb[base];           xr1 = emb[base + DIM];
        xr2 = emb[base + 2*DIM];   xr3 = emb[base + 3*DIM];
    }

    while (q < nquads) {
        int qn = q + stride;                 // scan to next live quad (no loads)
        while (qn < nquads && !QLIVE(qn)) qn += stride;

        // stage current quad (in-wave write->read, lgkmcnt ordering)
        xrow[wave][0][lane] = bfr(xr0);
        xrow[wave][1][lane] = bfr(xr1);
        xrow[wave][2][lane] = bfr(xr2);
        xrow[wave][3][lane] = bfr(xr3);

        float xn0 = 0.f, xn1 = 0.f, xn2 = 0.f, xn3 = 0.f;
        if (qn < nquads) {                   // prefetch next live quad
            const size_t base = (size_t)(4*qn) * DIM + lane;
            xn0 = emb[base];           xn1 = emb[base + DIM];
            xn2 = emb[base + 2*DIM];   xn3 = emb[base + 3*DIM];
        }

        const int t   = (4*q) & (T2 - 1);
        const int len = lengths[(4*q) >> 11];

        const float4* xv0 = (const float4*)xrow[wave][0];
        const float4* xv1 = (const float4*)xrow[wave][1];
        const float4* xv2 = (const float4*)xrow[wave][2];
        const float4* xv3 = (const float4*)xrow[wave][3];
        float a0 = 0.f, a1 = 0.f, a2 = 0.f, a3 = 0.f;   // 4 independent chains
        #pragma unroll
        for (int qq = 0; qq < 16; ++qq) {
            float4 u = xv0[qq]; float4 v = xv1[qq];
            float4 w = xv2[qq]; float4 x = xv3[qq];
            CH(a0, u.x, wx[4*qq+0]); CH(a1, v.x, wx[4*qq+0]);
            CH(a2, w.x, wx[4*qq+0]); CH(a3, x.x, wx[4*qq+0]);
            CH(a0, u.y, wx[4*qq+1]); CH(a1, v.y, wx[4*qq+1]);
            CH(a2, w.y, wx[4*qq+1]); CH(a3, x.y, wx[4*qq+1]);
            CH(a0, u.z, wx[4*qq+2]); CH(a1, v.z, wx[4*qq+2]);
            CH(a2, w.z, wx[4*qq+2]); CH(a3, x.z, wx[4*qq+2]);
            CH(a0, u.w, wx[4*qq+3]); CH(a1, v.w, wx[4*qq+3]);
            CH(a2, w.w, wx[4*qq+3]); CH(a3, x.w, wx[4*qq+3]);
        }
        if (lane < NG) {
            const size_t pb = (size_t)(4*q) * NG + g;
            pa[pb] = (unsigned short)(__float_as_uint(a0) >> 16);
            if (t + 1 < len) pa[pb +   NG] = (unsigned short)(__float_as_uint(a1) >> 16);
            if (t + 2 < len) pa[pb + 2*NG] = (unsigned short)(__float_as_uint(a2) >> 16);
            if (t + 3 < len) pa[pb + 3*NG] = (unsigned short)(__float_as_uint(a3) >> 16);
        }
        q = qn;
        xr0 = xn0; xr1 = xn1; xr2 = xn2; xr3 = xn3;
    }
    #undef QLIVE
}

// ====== Phase 2: deep-ring layer pipeline (R16 exact — proven best) ======
__global__ __launch_bounds__(256, 1)
void lstm4_pipe(const int* __restrict__ lengths,
                const unsigned short* __restrict__ pa,
                const float* __restrict__ Wihr,
                const float* __restrict__ Whh,
                const float* __restrict__ bih,
                const float* __restrict__ bhh,
                float* __restrict__ out)
{
    const int s    = blockIdx.x;
    const int wave = threadIdx.x >> 6;     // = layer index l
    const int lane = threadIdx.x & 63;
    const int g    = (lane < NG) ? lane : (NG - 1);

    __shared__ __align__(16) float ring[NLAY-1][RS][16];   // layers 0..2 publish

    const int l = wave;
    float wr[16], wi[16];
    #pragma unroll
    for (int j = 0; j < HID; ++j) wr[j] = bfr(Whh[(l*NG + g)*HID + j]);
    wr[15] = 0.0f;
    if (l > 0) {
        #pragma unroll
        for (int j = 0; j < HID; ++j) wi[j] = bfr(Wihr[((l-1)*NG + g)*HID + j]);
        wi[15] = 0.0f;
    } else {
        #pragma unroll
        for (int j = 0; j < 16; ++j) wi[j] = 0.0f;
    }
    const float bias_ = bfr(bfr(bih[l*NG + g]) + bfr(bhh[l*NG + g]));

    int len = lengths[s];
    len = len < 1 ? 1 : (len > T2 ? T2 : len);
    const unsigned short* pas = pa + (size_t)s * T2 * NG;

    float c_ = 0.0f;
    float hs[HID];
    #pragma unroll
    for (int j = 0; j < HID; ++j) hs[j] = 0.0f;

    unsigned pan_c[DG], pan_n[DG];
    if (l == 0) {
        #pragma unroll
        for (int d = 0; d < DG; ++d) {
            const int tt = (d < len) ? d : (len - 1);
            pan_n[d] = pas[(size_t)tt * NG + g];
        }
    }

    const bool tg = (lane >= 30 && lane < 45);
    const int ngrp = (len + DG - 1) / DG;
    const int G    = ngrp + NLAY - 1;

    for (int grp = 0; grp < G; ++grp) {
        const int myg = grp - l;
        if (myg >= 0 && myg < ngrp) {        // wave-uniform
            const int t0 = myg * DG;

            if (l == 0) {
                #pragma unroll
                for (int d = 0; d < DG; ++d) pan_c[d] = pan_n[d];
                #pragma unroll
                for (int d = 0; d < DG; ++d) {
                    int tt = t0 + DG + d; tt = (tt < len) ? tt : (len - 1);
                    pan_n[d] = pas[(size_t)tt * NG + g];
                }
            }

            #pragma unroll
            for (int d = 0; d < DG; ++d) {   // 8 supersteps, NO barrier inside
                const int t = t0 + d;
                if (t < len) {               // wave-uniform
                    float a_in = 0.0f, a_rec = 0.0f;
                    float hv[16];

                    if (l > 0) {             // issue LDS reads early
                        const float4* hp = (const float4*)ring[l-1][t & (RS-1)];
                        *(float4*)&hv[0]  = hp[0]; *(float4*)&hv[4]  = hp[1];
                        *(float4*)&hv[8]  = hp[2]; *(float4*)&hv[12] = hp[3];
                    }

                    #pragma unroll
                    for (int j = 0; j < HID; ++j) CH(a_rec, hs[j], wr[j]);

                    if (l == 0) {
                        a_in = b2f(pan_c[d]);
                    } else {
                        #pragma unroll
                        for (int j = 0; j < HID; ++j) CH(a_in, hv[j], wi[j]);
                    }

                    const float z = bfr(bfr(a_in + a_rec) + bias_);

                    const float arg = tg ? (-2.0f * z) : (-z);
                    const float e   = __expf(arg);
                    const float es  = bfr(e);               // sig tail
                    const float dn  = bfr(1.0f + es);
                    const float rsg = bfr(1.0f / dn);
                    const float rth = bfr((1.0f - e) / (1.0f + e));  // tanh tail
                    const float a   = tg ? rth : rsg;

                    const float fv = __shfl(a, (lane + 15) & 63);
                    const float gv = __shfl(a, (lane + 30) & 63);
                    const float ov = __shfl(a, (lane + 45) & 63);

                    const float cn = bfr(bfr(fv * c_) + bfr(a * gv));
                    c_ = cn;
                    const float hn = bfr(ov * tanh_np(cn));

                    #pragma unroll
                    for (int j = 0; j < HID; ++j)
                        hs[j] = __uint_as_float(__builtin_amdgcn_readlane(__float_as_uint(hn), j));

                    if (l < NLAY - 1 && lane < HID) ring[l][t & (RS-1)][lane] = hn;
                    if (l == NLAY - 1 && t == len - 1 && lane < HID)
                        out[s * HID + lane] = hn;
                }
            }
        }
        __syncthreads();                     // one barrier per group
    }
}

// ============ Fallback (round-6, passing): used if ws too small ============
__global__ __launch_bounds__(64, 1)
void lstm4_bf16np(const float* __restrict__ emb,
                  const int*   __restrict__ lengths,
                  const float* __restrict__ Wih0,
                  const float* __restrict__ Wihr,
                  const float* __restrict__ Whh,
                  const float* __restrict__ bih,
                  const float* __restrict__ bhh,
                  float* __restrict__ out)
{
    const int s    = blockIdx.x;
    const int lane = threadIdx.x;
    const int g    = (lane < NG) ? lane : (NG - 1);

    __shared__ __align__(16) float x_lds[DIM];
    __shared__ __align__(16) float h_lds[NLAY][16];

    float wx[DIM];
    #pragma unroll
    for (int q = 0; q < DIM/4; ++q) {
        float4 w = *(const float4*)(Wih0 + g*DIM + 4*q);
        wx[4*q+0] = bfr(w.x); wx[4*q+1] = bfr(w.y);
        wx[4*q+2] = bfr(w.z); wx[4*q+3] = bfr(w.w);
    }
    float wr[NLAY][16]; float wi[NLAY-1][16]; float bias[NLAY];
    #pragma unroll
    for (int l = 0; l < NLAY; ++l) {
        #pragma unroll
        for (int j = 0; j < HID; ++j) wr[l][j] = bfr(Whh[(l*NG + g)*HID + j]);
        wr[l][15] = 0.0f;
        bias[l] = bfr(bfr(bih[l*NG + g]) + bfr(bhh[l*NG + g]));
    }
    #pragma unroll
    for (int l = 0; l < NLAY-1; ++l) {
        #pragma unroll
        for (int j = 0; j < HID; ++j) wi[l][j] = bfr(Wihr[(l*NG + g)*HID + j]);
        wi[l][15] = 0.0f;
    }
    if (lane < 16) {
        #pragma unroll
        for (int l = 0; l < NLAY; ++l) h_lds[l][lane] = 0.0f;
    }
    float c[NLAY] = {0.0f, 0.0f, 0.0f, 0.0f};
    int len = lengths[s];
    len = len < 1 ? 1 : (len > T2 ? T2 : len);
    const float* xb = emb + (size_t)s * T2 * DIM;
    x_lds[lane] = bfr(xb[lane]);
    __syncthreads();
    const bool tg = (lane >= 30 && lane < 45);
    const float4* x4 = (const float4*)x_lds;
    float hout = 0.0f;
    for (int t = 0; t < len; ++t) {
        const int tn = (t + 1 < len) ? (t + 1) : t;
        const float xn = bfr(xb[(size_t)tn * DIM + lane]);
        #pragma unroll
        for (int l = 0; l < NLAY; ++l) {
            float a_in = 0.0f;
            if (l == 0) {
                #pragma unroll
                for (int q = 0; q < 16; ++q) {
                    float4 v = x4[q];
                    CH(a_in, v.x, wx[4*q+0]); CH(a_in, v.y, wx[4*q+1]);
                    CH(a_in, v.z, wx[4*q+2]); CH(a_in, v.w, wx[4*q+3]);
                }
            } else {
                const float4* hp = (const float4*)h_lds[l-1];
                float hv[16];
                *(float4*)&hv[0]  = hp[0]; *(float4*)&hv[4]  = hp[1];
                *(float4*)&hv[8]  = hp[2]; *(float4*)&hv[12] = hp[3];
                #pragma unroll
                for (int j = 0; j < HID; ++j) CH(a_in, hv[j], wi[l-1][j]);
            }
            float a_rec = 0.0f;
            {
                const float4* hc = (const float4*)h_lds[l];
                float hv[16];
                *(float4*)&hv[0]  = hc[0]; *(float4*)&hv[4]  = hc[1];
                *(float4*)&hv[8]  = hc[2]; *(float4*)&hv[12] = hc[3];
                #pragma unroll
                for (int j = 0; j < HID; ++j) CH(a_rec, hv[j], wr[l][j]);
            }
            const float z = bfr(bfr(a_in + a_rec) + bias[l]);
            const float a = tg ? tanh_np(z) : sig_np(z);
            const float fv = __shfl(a, (lane + 15) & 63);
            const float gv = __shfl(a, (lane + 30) & 63);
            const float ov = __shfl(a, (lane + 45) & 63);
            const float cn = bfr(bfr(fv * c[l]) + bfr(a * gv));
            c[l] = cn;
            const float hn = bfr(ov * tanh_np(cn));
            if (lane < HID) h_lds[l][lane] = hn;
            if (l == NLAY-1 && t == len-1) hout = hn;
        }
        x_lds[lane] = xn;
    }
    if (lane < HID) out[s * HID + lane] = hout;
}

extern "C" void kernel_launch(void* const* d_in, const int* in_sizes, int n_in,
                              void* d_out, int out_size, void* d_ws, size_t ws_size,
                              hipStream_t stream) {
    const float* emb     = (const float*)d_in[0];
    const int*   lengths = (const int*)  d_in[1];
    const float* Wih0    = (const float*)d_in[2];
    const float* Wihr    = (const float*)d_in[3];
    const float* Whh     = (const float*)d_in[4];
    const float* bih     = (const float*)d_in[5];
    const float* bhh     = (const float*)d_in[6];
    float* out = (float*)d_out;

    const size_t need = (size_t)BSZ * T2 * NG * sizeof(unsigned short);
    if (ws_size >= need) {
        unsigned short* pa = (unsigned short*)d_ws;
        proj0<<<2048, 256, 0, stream>>>(emb, lengths, Wih0, pa);
        lstm4_pipe<<<BSZ, 256, 0, stream>>>(lengths, pa, Wihr, Whh, bih, bhh, out);
    } else {
        lstm4_bf16np<<<BSZ, 64, 0, stream>>>(emb, lengths, Wih0, Wihr, Whh, bih, bhh, out);
    }
}

// Round 18
// 2065.478 us; speedup vs baseline: 1.0755x; 1.0755x over previous
//
#include <hip/hip_runtime.h>
#include <hip/hip_bf16.h>

#define HID 15
#define NG  60      // 4*HID
#define DIM 64
#define T2  2048
#define NLAY 4
#define BSZ 512
#define DG  8       // supersteps per barrier group (layer skew depth)
#define RS  16      // h-ring slots = 2*DG

// bf16 RNE rounding via compiler's __float2bfloat16 — PROVEN R15/R16.
__device__ __forceinline__ float bfr(float x) {
    __hip_bfloat16 h = __float2bfloat16(x);
    unsigned short u;
    __builtin_memcpy(&u, &h, 2);
    return __uint_as_float(((unsigned)u) << 16);
}
// one bf16-rounded multiply-accumulate term: acc = bf(acc + bf(a*b))
#define CH(acc, a, b) acc = bfr(acc + bfr((a) * (b)))

__device__ __forceinline__ float tanh_np(float z) {
    const float e = __expf(-2.0f * z);
    return bfr((1.0f - e) / (1.0f + e));
}
__device__ __forceinline__ float sig_np(float z) {
    const float e   = bfr(__expf(-z));
    const float den = bfr(1.0f + e);
    return bfr(1.0f / den);
}
__device__ __forceinline__ float b2f(unsigned b) {
    return __uint_as_float(b << 16);
}

// ============ Phase 1: layer-0 projection (R16 EXACT — proven best) ============
// 2 rows/wave + dead-row load skip. R17's 4-row variant regressed (VGPR
// occupancy quantum) — do not revisit.
__global__ __launch_bounds__(256, 1)
void proj0(const float* __restrict__ emb,
           const int*   __restrict__ lengths,
           const float* __restrict__ Wih0,
           unsigned short* __restrict__ pa)
{
    const int wave = threadIdx.x >> 6;
    const int lane = threadIdx.x & 63;
    const int g    = (lane < NG) ? lane : (NG - 1);

    __shared__ __align__(16) float xrow[4][2][64];

    float wx[DIM];
    #pragma unroll
    for (int q = 0; q < 16; ++q) {
        float4 w = *(const float4*)(Wih0 + g*DIM + 4*q);
        wx[4*q+0] = bfr(w.x); wx[4*q+1] = bfr(w.y);
        wx[4*q+2] = bfr(w.z); wx[4*q+3] = bfr(w.w);
    }

    const int npairs = (BSZ * T2) / 2;
    const int stride = gridDim.x * 4;

    #define LIVE(p, tt, bb) (((tt) = (2*(p)) & (T2-1)), ((bb) = (2*(p)) >> 11), \
                             ((tt) < lengths[(bb)]))

    int t_, b_;
    int r = blockIdx.x * 4 + wave;
    while (r < npairs && !LIVE(r, t_, b_)) r += stride;   // first live pair

    float xr0 = 0.0f, xr1 = 0.0f;
    if (r < npairs) {                        // prime pipeline
        xr0 = emb[(size_t)(2*r)     * DIM + lane];
        xr1 = emb[(size_t)(2*r + 1) * DIM + lane];
    }

    while (r < npairs) {
        int rn = r + stride;                 // scan to next live pair (no loads)
        while (rn < npairs && !LIVE(rn, t_, b_)) rn += stride;

        float xn0 = 0.0f, xn1 = 0.0f;
        if (rn < npairs) {                   // prefetch next live pair
            xn0 = emb[(size_t)(2*rn)     * DIM + lane];
            xn1 = emb[(size_t)(2*rn + 1) * DIM + lane];
        }

        const int t   = (2*r) & (T2 - 1);
        const int len = lengths[(2*r) >> 11];

        xrow[wave][0][lane] = bfr(xr0);      // in-wave write->read (lgkmcnt)
        xrow[wave][1][lane] = bfr(xr1);
        const float4* xv0 = (const float4*)xrow[wave][0];
        const float4* xv1 = (const float4*)xrow[wave][1];
        float a0 = 0.0f, a1 = 0.0f;          // two independent chains
        #pragma unroll
        for (int q = 0; q < 16; ++q) {
            float4 u = xv0[q]; float4 v = xv1[q];
            CH(a0, u.x, wx[4*q+0]); CH(a1, v.x, wx[4*q+0]);
            CH(a0, u.y, wx[4*q+1]); CH(a1, v.y, wx[4*q+1]);
            CH(a0, u.z, wx[4*q+2]); CH(a1, v.z, wx[4*q+2]);
            CH(a0, u.w, wx[4*q+3]); CH(a1, v.w, wx[4*q+3]);
        }
        if (lane < NG) {
            pa[(size_t)(2*r) * NG + g] = (unsigned short)(__float_as_uint(a0) >> 16);
            if (t + 1 < len)
                pa[(size_t)(2*r + 1) * NG + g] = (unsigned short)(__float_as_uint(a1) >> 16);
        }
        r = rn; xr0 = xn0; xr1 = xn1;
    }
    #undef LIVE
}

// ====== Phase 2: deep-ring pipeline (R16) + EXPLICIT MUL-HOISTING ======
// CH's products bfr(h[j]*w[j]) are dataflow-independent of the accumulator;
// only add+cvt pairs are serial. Hoisting the 15 muls+cvts ahead of the add
// tail halves the dependent chain IF the compiler wasn't already doing it.
// Values identical (FP mul deterministic; accumulator rounding sequence
// unchanged) -> bit-identical output.
__global__ __launch_bounds__(256, 1)
void lstm4_pipe(const int* __restrict__ lengths,
                const unsigned short* __restrict__ pa,
                const float* __restrict__ Wihr,
                const float* __restrict__ Whh,
                const float* __restrict__ bih,
                const float* __restrict__ bhh,
                float* __restrict__ out)
{
    const int s    = blockIdx.x;
    const int wave = threadIdx.x >> 6;     // = layer index l
    const int lane = threadIdx.x & 63;
    const int g    = (lane < NG) ? lane : (NG - 1);

    __shared__ __align__(16) float ring[NLAY-1][RS][16];   // layers 0..2 publish

    const int l = wave;
    float wr[16], wi[16];
    #pragma unroll
    for (int j = 0; j < HID; ++j) wr[j] = bfr(Whh[(l*NG + g)*HID + j]);
    wr[15] = 0.0f;
    if (l > 0) {
        #pragma unroll
        for (int j = 0; j < HID; ++j) wi[j] = bfr(Wihr[((l-1)*NG + g)*HID + j]);
        wi[15] = 0.0f;
    } else {
        #pragma unroll
        for (int j = 0; j < 16; ++j) wi[j] = 0.0f;
    }
    const float bias_ = bfr(bfr(bih[l*NG + g]) + bfr(bhh[l*NG + g]));

    int len = lengths[s];
    len = len < 1 ? 1 : (len > T2 ? T2 : len);
    const unsigned short* pas = pa + (size_t)s * T2 * NG;

    float c_ = 0.0f;
    float hs[HID];
    #pragma unroll
    for (int j = 0; j < HID; ++j) hs[j] = 0.0f;

    unsigned pan_c[DG], pan_n[DG];
    if (l == 0) {
        #pragma unroll
        for (int d = 0; d < DG; ++d) {
            const int tt = (d < len) ? d : (len - 1);
            pan_n[d] = pas[(size_t)tt * NG + g];
        }
    }

    const bool tg = (lane >= 30 && lane < 45);
    const int ngrp = (len + DG - 1) / DG;
    const int G    = ngrp + NLAY - 1;

    for (int grp = 0; grp < G; ++grp) {
        const int myg = grp - l;
        if (myg >= 0 && myg < ngrp) {        // wave-uniform
            const int t0 = myg * DG;

            if (l == 0) {
                #pragma unroll
                for (int d = 0; d < DG; ++d) pan_c[d] = pan_n[d];
                #pragma unroll
                for (int d = 0; d < DG; ++d) {
                    int tt = t0 + DG + d; tt = (tt < len) ? tt : (len - 1);
                    pan_n[d] = pas[(size_t)tt * NG + g];
                }
            }

            #pragma unroll
            for (int d = 0; d < DG; ++d) {   // 8 supersteps, NO barrier inside
                const int t = t0 + d;
                if (t < len) {               // wave-uniform
                    float a_in = 0.0f, a_rec = 0.0f;
                    float hv[16];

                    if (l > 0) {             // issue LDS reads early
                        const float4* hp = (const float4*)ring[l-1][t & (RS-1)];
                        *(float4*)&hv[0]  = hp[0]; *(float4*)&hv[4]  = hp[1];
                        *(float4*)&hv[8]  = hp[2]; *(float4*)&hv[12] = hp[3];
                    }

                    // ---- mul-hoist: all products first (independent) ----
                    float mr[HID];
                    #pragma unroll
                    for (int j = 0; j < HID; ++j) mr[j] = bfr(hs[j] * wr[j]);

                    float mi[HID];
                    if (l > 0) {
                        #pragma unroll
                        for (int j = 0; j < HID; ++j) mi[j] = bfr(hv[j] * wi[j]);
                    }

                    // ---- serial add tails (the true dependent chains) ----
                    #pragma unroll
                    for (int j = 0; j < HID; ++j) a_rec = bfr(a_rec + mr[j]);

                    if (l == 0) {
                        a_in = b2f(pan_c[d]);
                    } else {
                        #pragma unroll
                        for (int j = 0; j < HID; ++j) a_in = bfr(a_in + mi[j]);
                    }

                    const float z = bfr(bfr(a_in + a_rec) + bias_);

                    const float arg = tg ? (-2.0f * z) : (-z);
                    const float e   = __expf(arg);
                    const float es  = bfr(e);               // sig tail
                    const float dn  = bfr(1.0f + es);
                    const float rsg = bfr(1.0f / dn);
                    const float rth = bfr((1.0f - e) / (1.0f + e));  // tanh tail
                    const float a   = tg ? rth : rsg;

                    const float fv = __shfl(a, (lane + 15) & 63);
                    const float gv = __shfl(a, (lane + 30) & 63);
                    const float ov = __shfl(a, (lane + 45) & 63);

                    const float cn = bfr(bfr(fv * c_) + bfr(a * gv));
                    c_ = cn;
                    const float hn = bfr(ov * tanh_np(cn));

                    #pragma unroll
                    for (int j = 0; j < HID; ++j)
                        hs[j] = __uint_as_float(__builtin_amdgcn_readlane(__float_as_uint(hn), j));

                    if (l < NLAY - 1 && lane < HID) ring[l][t & (RS-1)][lane] = hn;
                    if (l == NLAY - 1 && t == len - 1 && lane < HID)
                        out[s * HID + lane] = hn;
                }
            }
        }
        __syncthreads();                     // one barrier per group
    }
}

// ============ Fallback (round-6, passing): used if ws too small ============
__global__ __launch_bounds__(64, 1)
void lstm4_bf16np(const float* __restrict__ emb,
                  const int*   __restrict__ lengths,
                  const float* __restrict__ Wih0,
                  const float* __restrict__ Wihr,
                  const float* __restrict__ Whh,
                  const float* __restrict__ bih,
                  const float* __restrict__ bhh,
                  float* __restrict__ out)
{
    const int s    = blockIdx.x;
    const int lane = threadIdx.x;
    const int g    = (lane < NG) ? lane : (NG - 1);

    __shared__ __align__(16) float x_lds[DIM];
    __shared__ __align__(16) float h_lds[NLAY][16];

    float wx[DIM];
    #pragma unroll
    for (int q = 0; q < DIM/4; ++q) {
        float4 w = *(const float4*)(Wih0 + g*DIM + 4*q);
        wx[4*q+0] = bfr(w.x); wx[4*q+1] = bfr(w.y);
        wx[4*q+2] = bfr(w.z); wx[4*q+3] = bfr(w.w);
    }
    float wr[NLAY][16]; float wi[NLAY-1][16]; float bias[NLAY];
    #pragma unroll
    for (int l = 0; l < NLAY; ++l) {
        #pragma unroll
        for (int j = 0; j < HID; ++j) wr[l][j] = bfr(Whh[(l*NG + g)*HID + j]);
        wr[l][15] = 0.0f;
        bias[l] = bfr(bfr(bih[l*NG + g]) + bfr(bhh[l*NG + g]));
    }
    #pragma unroll
    for (int l = 0; l < NLAY-1; ++l) {
        #pragma unroll
        for (int j = 0; j < HID; ++j) wi[l][j] = bfr(Wihr[(l*NG + g)*HID + j]);
        wi[l][15] = 0.0f;
    }
    if (lane < 16) {
        #pragma unroll
        for (int l = 0; l < NLAY; ++l) h_lds[l][lane] = 0.0f;
    }
    float c[NLAY] = {0.0f, 0.0f, 0.0f, 0.0f};
    int len = lengths[s];
    len = len < 1 ? 1 : (len > T2 ? T2 : len);
    const float* xb = emb + (size_t)s * T2 * DIM;
    x_lds[lane] = bfr(xb[lane]);
    __syncthreads();
    const bool tg = (lane >= 30 && lane < 45);
    const float4* x4 = (const float4*)x_lds;
    float hout = 0.0f;
    for (int t = 0; t < len; ++t) {
        const int tn = (t + 1 < len) ? (t + 1) : t;
        const float xn = bfr(xb[(size_t)tn * DIM + lane]);
        #pragma unroll
        for (int l = 0; l < NLAY; ++l) {
            float a_in = 0.0f;
            if (l == 0) {
                #pragma unroll
                for (int q = 0; q < 16; ++q) {
                    float4 v = x4[q];
                    CH(a_in, v.x, wx[4*q+0]); CH(a_in, v.y, wx[4*q+1]);
                    CH(a_in, v.z, wx[4*q+2]); CH(a_in, v.w, wx[4*q+3]);
                }
            } else {
                const float4* hp = (const float4*)h_lds[l-1];
                float hv[16];
                *(float4*)&hv[0]  = hp[0]; *(float4*)&hv[4]  = hp[1];
                *(float4*)&hv[8]  = hp[2]; *(float4*)&hv[12] = hp[3];
                #pragma unroll
                for (int j = 0; j < HID; ++j) CH(a_in, hv[j], wi[l-1][j]);
            }
            float a_rec = 0.0f;
            {
                const float4* hc = (const float4*)h_lds[l];
                float hv[16];
                *(float4*)&hv[0]  = hc[0]; *(float4*)&hv[4]  = hc[1];
                *(float4*)&hv[8]  = hc[2]; *(float4*)&hv[12] = hc[3];
                #pragma unroll
                for (int j = 0; j < HID; ++j) CH(a_rec, hv[j], wr[l][j]);
            }
            const float z = bfr(bfr(a_in + a_rec) + bias[l]);
            const float a = tg ? tanh_np(z) : sig_np(z);
            const float fv = __shfl(a, (lane + 15) & 63);
            const float gv = __shfl(a, (lane + 30) & 63);
            const float ov = __shfl(a, (lane + 45) & 63);
            const float cn = bfr(bfr(fv * c[l]) + bfr(a * gv));
            c[l] = cn;
            const float hn = bfr(ov * tanh_np(cn));
            if (lane < HID) h_lds[l][lane] = hn;
            if (l == NLAY-1 && t == len-1) hout = hn;
        }
        x_lds[lane] = xn;
    }
    if (lane < HID) out[s * HID + lane] = hout;
}

extern "C" void kernel_launch(void* const* d_in, const int* in_sizes, int n_in,
                              void* d_out, int out_size, void* d_ws, size_t ws_size,
                              hipStream_t stream) {
    const float* emb     = (const float*)d_in[0];
    const int*   lengths = (const int*)  d_in[1];
    const float* Wih0    = (const float*)d_in[2];
    const float* Wihr    = (const float*)d_in[3];
    const float* Whh     = (const float*)d_in[4];
    const float* bih     = (const float*)d_in[5];
    const float* bhh     = (const float*)d_in[6];
    float* out = (float*)d_out;

    const size_t need = (size_t)BSZ * T2 * NG * sizeof(unsigned short);
    if (ws_size >= need) {
        unsigned short* pa = (unsigned short*)d_ws;
        proj0<<<2048, 256, 0, stream>>>(emb, lengths, Wih0, pa);
        lstm4_pipe<<<BSZ, 256, 0, stream>>>(lengths, pa, Wihr, Whh, bih, bhh, out);
    } else {
        lstm4_bf16np<<<BSZ, 64, 0, stream>>>(emb, lengths, Wih0, Wihr, Whh, bih, bhh, out);
    }
}